// Round 3
// baseline (168.407 us; speedup 1.0000x reference)
//
#include <hip/hip_runtime.h>

#define LAMBDA_COORD 5.0f
#define LAMBDA_NOOBJ 0.5f

constexpr int Bn = 64;       // batch
constexpr int An = 10647;    // anchors
constexpr int Cn = 9;        // classes
constexpr int Gn = 50;       // gt boxes
constexpr int PRED_ROW = 5 + Cn;        // 14 floats per anchor row
constexpr int S  = 16;                  // anchor splits
constexpr int AC = (An + S - 1) / S;    // 666 anchors per split
constexpr int ACP = 704;                // 11*64: scan is 11 iters; 666 <= 704
constexpr int GTW = 7;                  // GT slots per wave per pass

// ws layout (all poisoned by harness each iteration -> only write-then-read):
//   partials : Bn*Gn*S float2 (score, idx-as-bits)  = 409600 B
//   bcepart  : Bn*S floats                           = 4096 B
//   per_img  : Bn floats                             = 256 B
//
// Ticket counters CANNOT live in ws (poison is unknown, and a racing in-kernel
// init is unsound once k1 blocks themselves take tickets). Module .bss globals
// are zero-init at load and NOT poisoned; each launch adds exactly 16 tickets
// per image and 64 image-tickets, so "last" is (old+1) % {16,64} == 0 --
// correct for ANY number of launches (warmup, graph replay, rocprof replay).
__device__ int g_cntB[Bn];   // per-image completion tickets (+16 per launch)
__device__ int g_cnt2;       // per-launch image tickets      (+64 per launch)

// Fused kernel: k1 (IoU argmax partials) + per-image tail (old k2) + final
// reduction (old k3). The per-image last block's tail overlaps the remaining
// k1 blocks instead of waiting behind a full device drain + dispatch gap.
//
// Cross-XCD visibility: writers do plain stores -> __syncthreads (drains
// vmcnt) -> __threadfence (agent fence: buffer_wbl2) -> device atomic ticket.
// Reader: atomic ticket -> __threadfence (buffer_inv: kills poison-stale L2
// lines on its XCD) -> plain loads. per_img handoff stays pure-atomic.
__global__ __launch_bounds__(256, 4) void yolo_fused(
    const float* __restrict__ pred,     // [B, A, 14]
    const float* __restrict__ bboxes,   // [B, G, 4]
    const int*  __restrict__ classes,   // [B, G]
    float2* __restrict__ partials,      // [B, G, S]
    float* __restrict__ bcepart,        // [B, S]
    float* __restrict__ per_img,        // [B]
    float* __restrict__ out)            // [1]
{
    const int s = blockIdx.x;
    const int b = blockIdx.y;
    const int a0 = s * AC;
    const int n  = min(AC, An - a0);    // 666 (657 for last split)

    const int tid  = threadIdx.x;
    const int wave = tid >> 6;
    const int lane = tid & 63;

    __shared__ float4 sbox[ACP];  // x1,y1,x2,y2
    __shared__ float  sap[ACP];   // area_p
    __shared__ float  sred[4];
    __shared__ int    vgt[Gn];    // compacted valid GT indices (stable order)
    __shared__ int    svcnt;      // number of valid GTs
    __shared__ int    slast;      // 0 iff this block is last for image b

    // ---- stage anchors into LDS: branch-free loads, all hoisted ----
    const float* prow = pred + (size_t)b * An * PRED_ROW;
    float2 va[3], vb[3];
    float  vc[3];
    #pragma unroll
    for (int k = 0; k < 3; ++k) {
        int i   = tid + k * 256;                      // < 768 always
        int ild = min(i, n - 1);                      // clamped: load always valid
        const float* p = prow + (size_t)(a0 + ild) * PRED_ROW;
        va[k] = ((const float2*)p)[0];                // cx, cy  (8B-aligned: 56*a)
        vb[k] = ((const float2*)p)[1];                // w, h
        vc[k] = p[4];                                 // conf
    }
    float bce = 0.0f;
    #pragma unroll
    for (int k = 0; k < 3; ++k) {
        int  i     = tid + k * 256;
        bool valid = (i < n);
        float hw = 0.5f * vb[k].x, hh = 0.5f * vb[k].y;
        float x1 = va[k].x - hw, x2 = va[k].x + hw;
        float y1 = va[k].y - hh, y2 = va[k].y + hh;
        if (i < ACP) {
            // pad sentinel: iw<0 -> inter=0 -> never beats strict-> compare
            sbox[i] = valid ? make_float4(x1, y1, x2, y2)
                            : make_float4(1e30f, 1e30f, 1e30f, 1e30f);
            sap[i]  = valid ? (x2 - x1) * (y2 - y1) : 0.0f;
        }
        if (valid) bce -= fmaxf(__logf(1.0f - vc[k]), -100.0f);   // bce0
    }
    #pragma unroll
    for (int off = 32; off >= 1; off >>= 1) bce += __shfl_xor(bce, off, 64);
    if (lane == 0) sred[wave] = bce;

    // ---- wave 0: stable compaction of valid GT indices ----
    if (tid < 64) {
        int cls = (tid < Gn) ? classes[b * Gn + tid] : -1;
        unsigned long long msk = __ballot(cls != -1);
        if (cls != -1)
            vgt[__popcll(msk & ((1ull << tid) - 1))] = tid;
        if (tid == 0) svcnt = (int)__popcll(msk);
    }

    __syncthreads();
    if (tid == 0) bcepart[b * S + s] = sred[0] + sred[1] + sred[2] + sred[3];

    const int m = svcnt;                 // uniform across block
    const float* bb = bboxes + (size_t)b * Gn * 4;

    // ---- two passes over the COMPACTED list: slots 0..27 then 28..55 ----
    for (int pass = 0; pass < 2; ++pass) {
        const int g0s = pass * 28 + wave * GTW;      // slot base for this wave
        const int ngs = min(GTW, m - g0s);           // valid slots this wave
        if (ngs <= 0) continue;                      // wave-uniform skip

        float gx1[GTW], gy1[GTW], gx2[GTW], gy2[GTW], gc1[GTW];
        #pragma unroll
        for (int j = 0; j < GTW; ++j) {
            int slot = (j < ngs) ? (g0s + j) : g0s;  // pad tail with dup slot
            int g = vgt[slot];
            float b0 = bb[g * 4 + 0], b1 = bb[g * 4 + 1];
            float b2 = bb[g * 4 + 2], b3 = bb[g * 4 + 3];
            float gcx = 0.5f * (b0 + b2), gcy = 0.5f * (b1 + b3);
            float gw = b2 - b0, gh = b3 - b1;
            gx1[j] = gcx - gw * 0.5f; gx2[j] = gcx + gw * 0.5f;
            gy1[j] = gcy - gh * 0.5f; gy2[j] = gcy + gh * 0.5f;
            gc1[j] = (gx2[j] - gx1[j]) * (gy2[j] - gy1[j]) + 1e-16f;  // area_g+eps
        }

        float bnv[GTW], bdv[GTW];
        int   bidx[GTW];
        #pragma unroll
        for (int j = 0; j < GTW; ++j) { bnv[j] = 0.0f; bdv[j] = 1.0f; bidx[j] = 0; }

        // ---- main scan: branch-free, 7 IoUs per anchor read, 11 iters ----
        for (int base = 0; base < ACP; base += 64) {
            int i = base + lane;
            float4 pb = sbox[i];
            float  ap = sap[i];
            int   idx = a0 + i;
            #pragma unroll
            for (int j = 0; j < GTW; ++j) {
                float iw = fminf(pb.z, gx2[j]) - fmaxf(pb.x, gx1[j]);
                float ih = fminf(pb.w, gy2[j]) - fmaxf(pb.y, gy1[j]);
                iw = fmaxf(iw, 0.0f);
                ih = fmaxf(ih, 0.0f);
                float inter = iw * ih;
                float apc   = ap + gc1[j];
                // argmax of inter/(ap+ag-inter) == argmax of inter/(ap+ag):
                // r -> r/(1+r) monotone; compare fractions by cross-multiply.
                bool take = inter * bdv[j] > bnv[j] * apc;  // strict >: first max
                bnv[j]  = take ? inter : bnv[j];
                bdv[j]  = take ? apc   : bdv[j];
                bidx[j] = take ? idx   : bidx[j];
            }
        }

        // ---- cross-lane argmax per valid GT, write partial ----
        #pragma unroll
        for (int j = 0; j < GTW; ++j) {
            if (j < ngs) {
                float score = bnv[j] * __builtin_amdgcn_rcpf(bdv[j]); // monotone
                int   idx   = bidx[j];
                #pragma unroll
                for (int off = 1; off < 64; off <<= 1) {
                    float os = __shfl_xor(score, off, 64);
                    int   oi = __shfl_xor(idx, off, 64);
                    if (os > score) { score = os; idx = oi; }
                }
                if (lane == 0) {
                    int g = vgt[g0s + j];
                    partials[((size_t)b * Gn + g) * S + s] =
                        make_float2(score, __int_as_float(idx));
                }
            }
        }
    }

    // ---- per-image completion ticket (release) ----
    __syncthreads();            // all waves' partial/bcepart stores drained
    __threadfence();            // agent fence: write-back L2 -> device-visible
    if (tid == 0) slast = ((atomicAdd(&g_cntB[b], 1) + 1) & (S - 1));
    __syncthreads();
    if (slast != 0) return;     // not the last block of image b

    // ================= tail: old k2 body, wave 0 only =================
    if (tid >= 64) return;
    __threadfence();            // acquire: invalidate poison-stale L2 lines

    const int g = tid;          // lane g owns GT g
    int cls = (g < Gn) ? classes[b * Gn + g] : -1;

    float tot0 = 0.0f;
    #pragma unroll
    for (int t = 0; t < S; ++t) tot0 += bcepart[b * S + t];  // broadcast loads

    float per_gt = 0.0f;
    int   validf = (cls != -1) ? 1 : 0;
    if (validf) {
        const float2* pp = partials + ((size_t)b * Gn + g) * S;
        float2 c[S];
        #pragma unroll
        for (int t = 0; t < S; ++t) c[t] = pp[t];   // 16 parallel loads
        float best = -1.0f;
        int   bi = 0;
        #pragma unroll
        for (int t = 0; t < S; ++t)
            if (c[t].x > best) { best = c[t].x; bi = __float_as_int(c[t].y); }

        const float2* p2 = (const float2*)(pred + ((size_t)b * An + bi) * PRED_ROW);
        float2 r[7];
        #pragma unroll
        for (int q = 0; q < 7; ++q) r[q] = p2[q];   // 7 parallel loads (56 B row)
        float pcx = r[0].x, pcy = r[0].y, pw = r[1].x, ph = r[1].y, conf = r[2].x;

        const float* bbg = bboxes + ((size_t)b * Gn + g) * 4;
        float b0 = bbg[0], b1 = bbg[1], b2 = bbg[2], b3 = bbg[3];
        float gcx = 0.5f * (b0 + b2), gcy = 0.5f * (b1 + b3);
        float gw = b2 - b0, gh = b3 - b1;

        float dx = pcx - gcx, dy = pcy - gcy, dw = pw - gw, dh = ph - gh;
        float coord = LAMBDA_COORD * (dx * dx + dy * dy + dw * dw + dh * dh);

        float conf_obj = -fmaxf(__logf(conf), -100.0f);

        const float pcls[Cn] = { r[2].y, r[3].x, r[3].y, r[4].x, r[4].y,
                                 r[5].x, r[5].y, r[6].x, r[6].y };
        float clsl = 0.0f;
        #pragma unroll
        for (int c2 = 0; c2 < Cn; ++c2) {
            float pc = pcls[c2];
            float lp = fmaxf(__logf(pc), -100.0f);
            float ln = fmaxf(__logf(1.0f - pc), -100.0f);
            clsl -= (c2 == cls) ? lp : ln;
        }

        float bce0b = -fmaxf(__logf(1.0f - conf), -100.0f);
        float noobj = LAMBDA_NOOBJ * (tot0 - bce0b);

        per_gt = coord + conf_obj + clsl + noobj;
    }

    float sum = per_gt;
    int   anyv = validf;
    #pragma unroll
    for (int off = 1; off < 64; off <<= 1) {
        sum  += __shfl_xor(sum, off, 64);
        anyv |= __shfl_xor(anyv, off, 64);
    }

    float res = anyv ? sum : (LAMBDA_NOOBJ * tot0);

    // ---- final reduction (old k3), modular last-image ticket ----
    if (g == 0) atomicExch(&per_img[b], res);   // device-scope publish
    __threadfence();                            // order publish before ticket
    int t2 = 0;
    if (g == 0) t2 = atomicAdd(&g_cnt2, 1);
    t2 = __shfl(t2, 0, 64);
    if (((t2 + 1) & (Bn - 1)) == 0) {
        // all 64 publishes happened-before their tickets; read via atomics
        float v = atomicAdd(&per_img[g], 0.0f); // exact read (x + 0.0f == x)
        #pragma unroll
        for (int off = 1; off < 64; off <<= 1) v += __shfl_xor(v, off, 64);
        if (g == 0) out[0] = v * (1.0f / (float)Bn);
    }
}

extern "C" void kernel_launch(void* const* d_in, const int* in_sizes, int n_in,
                              void* d_out, int out_size, void* d_ws, size_t ws_size,
                              hipStream_t stream) {
    const float* pred    = (const float*)d_in[0];
    const float* bboxes  = (const float*)d_in[1];
    const int*   classes = (const int*)d_in[2];
    float* out = (float*)d_out;

    char* ws = (char*)d_ws;
    float2* partials = (float2*)ws;
    float*  bcepart  = (float*)(ws + (size_t)Bn * Gn * S * sizeof(float2));
    float*  per_img  = (float*)(ws + (size_t)Bn * Gn * S * sizeof(float2)
                                   + (size_t)Bn * S * sizeof(float));

    yolo_fused<<<dim3(S, Bn), 256, 0, stream>>>(pred, bboxes, classes,
                                                partials, bcepart, per_img, out);
}

// Round 4
// 102.479 us; speedup vs baseline: 1.6433x; 1.6433x over previous
//
#include <hip/hip_runtime.h>

#define LAMBDA_COORD 5.0f
#define LAMBDA_NOOBJ 0.5f

constexpr int Bn = 64;       // batch
constexpr int An = 10647;    // anchors
constexpr int Cn = 9;        // classes
constexpr int Gn = 50;       // gt boxes
constexpr int PRED_ROW = 5 + Cn;        // 14 floats per anchor row
constexpr int S  = 16;                  // anchor splits
constexpr int AC = (An + S - 1) / S;    // 666 anchors per split
constexpr int ACP = 704;                // 11*64: scan is 11 iters; 666 <= 704
constexpr int GTW = 7;                  // GTs per wave per pass (4*7=28; 2 passes)

// ws layout:
//   partials : Bn*Gn*S float2 (score, idx-as-bits)  = 409600 B
//   bcepart  : Bn*S floats                           = 4096 B
//   per_img  : Bn floats                             = 256 B
//   cnt      : 1 int (last-block ticket)             = 4 B
//
// MEASURED OPTIMUM (round 1: 104.0 us). Structure: 2 dispatches.
//  - k1: 16x64 blocks, VALU-bound IoU argmax scan (~10 us).
//  - k2: 64 blocks x 64 lanes, per-GT loss + fused final reduce via ticket.
// Total ~= 2 x 42.5 us harness poison-fill (256 MiB at write roofline,
// untouchable) + ~19 us kernels. Measured dead ends:
//  - GT compaction (round 2): overhead ~= savings, net +1.6 us.
//  - Full fusion w/ per-block agent fences (round 3): +60 us — __threadfence
//    on gfx950 = L2 writeback (buffer_wbl2) per block x 1024 blocks. Only
//    fence in tiny kernels (k2: 64 blocks) where it is free.
__global__ __launch_bounds__(256, 4) void yolo_k1(
    const float* __restrict__ pred,     // [B, A, 14]
    const float* __restrict__ bboxes,   // [B, G, 4]
    float2* __restrict__ partials,      // [B, G, S]
    float* __restrict__ bcepart,        // [B, S]
    int* __restrict__ cnt)              // ticket counter for fused k2 tail
{
    const int s = blockIdx.x;
    const int b = blockIdx.y;
    const int a0 = s * AC;
    const int n  = min(AC, An - a0);    // 666 (657 for last split)

    const int tid  = threadIdx.x;
    const int wave = tid >> 6;
    const int lane = tid & 63;

    // ws is poisoned each iteration: re-init the k2 ticket counter every
    // launch. k1->k2 kernel boundary on the stream guarantees visibility.
    if (tid == 0 && blockIdx.x == 0 && blockIdx.y == 0) *cnt = 0;

    __shared__ float4 sbox[ACP];  // x1,y1,x2,y2
    __shared__ float  sap[ACP];   // area_p
    __shared__ float  sred[4];

    // ---- stage anchors into LDS: branch-free loads, all hoisted ----
    const float* prow = pred + (size_t)b * An * PRED_ROW;
    float2 va[3], vb[3];
    float  vc[3];
    #pragma unroll
    for (int k = 0; k < 3; ++k) {
        int i   = tid + k * 256;                      // < 768 always
        int ild = min(i, n - 1);                      // clamped: load always valid
        const float* p = prow + (size_t)(a0 + ild) * PRED_ROW;
        va[k] = ((const float2*)p)[0];                // cx, cy  (8B-aligned: 56*a)
        vb[k] = ((const float2*)p)[1];                // w, h
        vc[k] = p[4];                                 // conf
    }
    float bce = 0.0f;
    #pragma unroll
    for (int k = 0; k < 3; ++k) {
        int  i     = tid + k * 256;
        bool valid = (i < n);
        float hw = 0.5f * vb[k].x, hh = 0.5f * vb[k].y;
        float x1 = va[k].x - hw, x2 = va[k].x + hw;
        float y1 = va[k].y - hh, y2 = va[k].y + hh;
        if (i < ACP) {
            // pad sentinel: iw<0 -> inter=0 -> never beats strict-> compare
            sbox[i] = valid ? make_float4(x1, y1, x2, y2)
                            : make_float4(1e30f, 1e30f, 1e30f, 1e30f);
            sap[i]  = valid ? (x2 - x1) * (y2 - y1) : 0.0f;
        }
        if (valid) bce -= fmaxf(__logf(1.0f - vc[k]), -100.0f);   // bce0
    }
    #pragma unroll
    for (int off = 32; off >= 1; off >>= 1) bce += __shfl_xor(bce, off, 64);
    if (lane == 0) sred[wave] = bce;

    __syncthreads();
    if (tid == 0) bcepart[b * S + s] = sred[0] + sred[1] + sred[2] + sred[3];

    const float* bb = bboxes + (size_t)b * Gn * 4;

    // ---- two passes: pass 0 -> GTs 0..27, pass 1 -> GTs 28..49 ----
    for (int pass = 0; pass < 2; ++pass) {
        const int g0 = pass * 28 + wave * GTW;
        const int ng = min(GTW, Gn - g0);   // 7,7,7,7 then 7,7,7,1

        float gx1[GTW], gy1[GTW], gx2[GTW], gy2[GTW], gc1[GTW];
        #pragma unroll
        for (int j = 0; j < GTW; ++j) {
            int g = (j < ng) ? (g0 + j) : g0;    // pad tail with duplicate GT
            float b0 = bb[g * 4 + 0], b1 = bb[g * 4 + 1];
            float b2 = bb[g * 4 + 2], b3 = bb[g * 4 + 3];
            float gcx = 0.5f * (b0 + b2), gcy = 0.5f * (b1 + b3);
            float gw = b2 - b0, gh = b3 - b1;
            gx1[j] = gcx - gw * 0.5f; gx2[j] = gcx + gw * 0.5f;
            gy1[j] = gcy - gh * 0.5f; gy2[j] = gcy + gh * 0.5f;
            gc1[j] = (gx2[j] - gx1[j]) * (gy2[j] - gy1[j]) + 1e-16f;  // area_g+eps
        }

        float bn[GTW], bd[GTW];
        int   bidx[GTW];
        #pragma unroll
        for (int j = 0; j < GTW; ++j) { bn[j] = 0.0f; bd[j] = 1.0f; bidx[j] = 0; }

        // ---- main scan: branch-free, 7 IoUs per anchor read, 11 iters ----
        for (int base = 0; base < ACP; base += 64) {
            int i = base + lane;
            float4 pb = sbox[i];
            float  ap = sap[i];
            int   idx = a0 + i;
            #pragma unroll
            for (int j = 0; j < GTW; ++j) {
                float iw = fminf(pb.z, gx2[j]) - fmaxf(pb.x, gx1[j]);
                float ih = fminf(pb.w, gy2[j]) - fmaxf(pb.y, gy1[j]);
                iw = fmaxf(iw, 0.0f);
                ih = fmaxf(ih, 0.0f);
                float inter = iw * ih;
                float apc   = ap + gc1[j];
                // argmax of inter/(ap+ag-inter) == argmax of inter/(ap+ag):
                // r -> r/(1+r) monotone; compare fractions by cross-multiply.
                bool take = inter * bd[j] > bn[j] * apc;  // strict >: first max
                bn[j]   = take ? inter : bn[j];
                bd[j]   = take ? apc   : bd[j];
                bidx[j] = take ? idx   : bidx[j];
            }
        }

        // ---- cross-lane argmax per GT, write partial ----
        #pragma unroll
        for (int j = 0; j < GTW; ++j) {
            if (j < ng) {
                float score = bn[j] * __builtin_amdgcn_rcpf(bd[j]); // monotone
                int   idx   = bidx[j];
                #pragma unroll
                for (int off = 1; off < 64; off <<= 1) {
                    float os = __shfl_xor(score, off, 64);
                    int   oi = __shfl_xor(idx, off, 64);
                    if (os > score) { score = os; idx = oi; }
                }
                if (lane == 0)
                    partials[((size_t)b * Gn + g0 + j) * S + s] =
                        make_float2(score, __int_as_float(idx));
            }
        }
    }
}

// k2: one block per image, 64 lanes; lane g owns GT g. __launch_bounds__(64,1)
// removes the VGPR cap so the 16-partial fold + pred row issue as parallel
// loads. Tail: last-block (ticket) pattern folds the old k3 into this kernel —
// the final 64-way reduce uses the exact same shuffle tree over the exact same
// per_img values, so the result is bitwise identical (absmax stays 0).
// Cross-XCD handoff goes through device-scope atomics; the fences here run in
// only 64 tiny blocks (measured free), unlike the round-3 per-k1-block fences.
__global__ __launch_bounds__(64, 1) void yolo_k2(
    const float* __restrict__ pred,
    const float* __restrict__ bboxes,
    const int*  __restrict__ classes,   // [B, G]
    const float2* __restrict__ partials,
    const float* __restrict__ bcepart,
    float* __restrict__ per_img,        // [B]
    int* __restrict__ cnt,
    float* __restrict__ out)
{
    const int b = blockIdx.x;
    const int g = threadIdx.x;

    int cls = (g < Gn) ? classes[b * Gn + g] : -1;

    float tot0 = 0.0f;
    #pragma unroll
    for (int s = 0; s < S; ++s) tot0 += bcepart[b * S + s];  // broadcast loads

    float per_gt = 0.0f;
    int   validf = 0;
    if (g < Gn) {
        validf = (cls != -1) ? 1 : 0;

        const float2* pp = partials + ((size_t)b * Gn + g) * S;
        float2 c[S];
        #pragma unroll
        for (int s = 0; s < S; ++s) c[s] = pp[s];   // 16 parallel loads
        float best = -1.0f;
        int   bi = 0;
        #pragma unroll
        for (int s = 0; s < S; ++s)
            if (c[s].x > best) { best = c[s].x; bi = __float_as_int(c[s].y); }

        const float2* p2 = (const float2*)(pred + ((size_t)b * An + bi) * PRED_ROW);
        float2 r[7];
        #pragma unroll
        for (int q = 0; q < 7; ++q) r[q] = p2[q];   // 7 parallel loads (56 B row)
        float pcx = r[0].x, pcy = r[0].y, pw = r[1].x, ph = r[1].y, conf = r[2].x;

        const float* bbg = bboxes + ((size_t)b * Gn + g) * 4;
        float b0 = bbg[0], b1 = bbg[1], b2 = bbg[2], b3 = bbg[3];
        float gcx = 0.5f * (b0 + b2), gcy = 0.5f * (b1 + b3);
        float gw = b2 - b0, gh = b3 - b1;

        float dx = pcx - gcx, dy = pcy - gcy, dw = pw - gw, dh = ph - gh;
        float coord = LAMBDA_COORD * (dx * dx + dy * dy + dw * dw + dh * dh);

        float conf_obj = -fmaxf(__logf(conf), -100.0f);

        const float pcls[Cn] = { r[2].y, r[3].x, r[3].y, r[4].x, r[4].y,
                                 r[5].x, r[5].y, r[6].x, r[6].y };
        float clsl = 0.0f;
        #pragma unroll
        for (int c2 = 0; c2 < Cn; ++c2) {
            float pc = pcls[c2];
            float lp = fmaxf(__logf(pc), -100.0f);
            float ln = fmaxf(__logf(1.0f - pc), -100.0f);
            clsl -= (c2 == cls) ? lp : ln;
        }

        float bce0b = -fmaxf(__logf(1.0f - conf), -100.0f);
        float noobj = LAMBDA_NOOBJ * (tot0 - bce0b);

        per_gt = coord + conf_obj + clsl + noobj;
        if (!validf) per_gt = 0.0f;
    }

    float sum = per_gt;
    int   anyv = validf;
    #pragma unroll
    for (int off = 1; off < 64; off <<= 1) {
        sum  += __shfl_xor(sum, off, 64);
        anyv |= __shfl_xor(anyv, off, 64);
    }

    float res = anyv ? sum : (LAMBDA_NOOBJ * tot0);

    // ---- fused final reduction (old k3), last-block pattern ----
    if (g == 0) atomicExch(&per_img[b], res);   // device-scope publish
    __threadfence();                            // order publish before ticket
    int ticket = 0;
    if (g == 0) ticket = atomicAdd(cnt, 1);
    ticket = __shfl(ticket, 0, 64);
    if (ticket == Bn - 1) {
        // all 64 publishes happened-before their tickets; read via atomics
        float v = atomicAdd(&per_img[g], 0.0f); // exact read (x + 0.0f == x)
        #pragma unroll
        for (int off = 1; off < 64; off <<= 1) v += __shfl_xor(v, off, 64);
        if (g == 0) out[0] = v * (1.0f / (float)Bn);
    }
}

extern "C" void kernel_launch(void* const* d_in, const int* in_sizes, int n_in,
                              void* d_out, int out_size, void* d_ws, size_t ws_size,
                              hipStream_t stream) {
    const float* pred    = (const float*)d_in[0];
    const float* bboxes  = (const float*)d_in[1];
    const int*   classes = (const int*)d_in[2];
    float* out = (float*)d_out;

    char* ws = (char*)d_ws;
    float2* partials = (float2*)ws;
    float*  bcepart  = (float*)(ws + (size_t)Bn * Gn * S * sizeof(float2));
    float*  per_img  = (float*)(ws + (size_t)Bn * Gn * S * sizeof(float2)
                                   + (size_t)Bn * S * sizeof(float));
    int*    cnt      = (int*)  (ws + (size_t)Bn * Gn * S * sizeof(float2)
                                   + (size_t)Bn * S * sizeof(float)
                                   + (size_t)Bn * sizeof(float));

    yolo_k1<<<dim3(S, Bn), 256, 0, stream>>>(pred, bboxes, partials, bcepart, cnt);
    yolo_k2<<<Bn, 64, 0, stream>>>(pred, bboxes, classes, partials, bcepart,
                                   per_img, cnt, out);
}